// Round 1
// baseline (1777.170 us; speedup 1.0000x reference)
//
#include <hip/hip_runtime.h>

#define NF 64   // IN_F == HID_F == 64

// ---------------- degree ----------------
__global__ void deg_kernel(const int* __restrict__ dst, float* __restrict__ deg, int E) {
    int e = blockIdx.x * blockDim.x + threadIdx.x;
    if (e < E) atomicAdd(&deg[dst[e]], 1.0f);
}

__global__ void dinv_kernel(float* __restrict__ deg, int n) {
    int i = blockIdx.x * blockDim.x + threadIdx.x;
    if (i < n) {
        float d = deg[i];
        deg[i] = rsqrtf(fmaxf(d, 1.0f));   // in-place: deg -> d^{-1/2}
    }
}

// ---------------- SpMM scatter: agg[dst] += X[src] * dinv[src] ----------------
// thread per (edge, feature); wave of 64 lanes == one edge's 64 features
__global__ void scatter_kernel(const float* __restrict__ X, const int* __restrict__ src,
                               const int* __restrict__ dst, const float* __restrict__ dinv,
                               float* __restrict__ agg, int E) {
    unsigned idx = blockIdx.x * blockDim.x + threadIdx.x;
    int e = (int)(idx >> 6);
    int f = (int)(idx & 63);
    if (e < E) {
        int s = src[e];
        int d = dst[e];
        float v = X[(size_t)s * NF + f] * dinv[s];
        atomicAdd(&agg[(size_t)d * NF + f], v);
    }
}

// ---------------- X1 = -agg * dinv[node] ----------------
__global__ void x1_kernel(const float* __restrict__ agg, const float* __restrict__ dinv,
                          float* __restrict__ X1, int total) {
    int idx = blockIdx.x * blockDim.x + threadIdx.x;
    if (idx < total) {
        int node = idx >> 6;
        X1[idx] = -agg[idx] * dinv[node];
    }
}

// ---------------- X2 = -2*agg*dinv[node] - X0   (in place over agg) ----------------
__global__ void x2_kernel(float* __restrict__ agg, const float* __restrict__ dinv,
                          const float* __restrict__ X0, int total) {
    int idx = blockIdx.x * blockDim.x + threadIdx.x;
    if (idx < total) {
        int node = idx >> 6;
        agg[idx] = -2.0f * agg[idx] * dinv[node] - X0[idx];
    }
}

// ---------------- GEMM: out[n, OUTF] = relu?([X0|X1|X2] @ W + b) ----------------
// Thread-per-node: acc[OUTF] in VGPRs; X rows staged in LDS (pad 65 -> stride%32==1,
// 2 lanes/bank for wave64 == conflict-free); W/bias indices are wave-uniform -> s_load.
template <int OUTF>
__launch_bounds__(256)
__global__ void gemm_cheb(const float* __restrict__ X0, const float* __restrict__ X1,
                          const float* __restrict__ X2, const float* __restrict__ W,
                          const float* __restrict__ bias, float* __restrict__ out,
                          int n, int do_relu) {
    __shared__ float xs[256 * 65];
    const int tid = threadIdx.x;
    const int node0 = blockIdx.x * 256;
    const int node = node0 + tid;

    float acc[OUTF];
#pragma unroll
    for (int j = 0; j < OUTF; ++j) acc[j] = bias[j];

    const float* Xp[3] = {X0, X1, X2};
#pragma unroll 1
    for (int p = 0; p < 3; ++p) {
        const float* __restrict__ Xc = Xp[p];
        // stage 256 node-rows (64 floats each) into LDS, float4 global reads
#pragma unroll
        for (int j = 0; j < 16; ++j) {
            int idx4 = j * 256 + tid;            // float4 index in [0, 4096)
            int ln = idx4 >> 4;                  // local node
            int k4 = (idx4 & 15) * 4;            // feature offset
            float4 v = make_float4(0.f, 0.f, 0.f, 0.f);
            int gnode = node0 + ln;
            if (gnode < n) v = *(const float4*)&Xc[(size_t)gnode * 64 + k4];
            float* s = &xs[ln * 65 + k4];
            s[0] = v.x; s[1] = v.y; s[2] = v.z; s[3] = v.w;
        }
        __syncthreads();

        const float* __restrict__ Wp = W + (size_t)p * 64 * OUTF;
        for (int k = 0; k < 64; ++k) {
            float x = xs[tid * 65 + k];
#pragma unroll
            for (int j = 0; j < OUTF; ++j)
                acc[j] += x * Wp[k * OUTF + j];
        }
        __syncthreads();
    }

    if (node < n) {
        float* o = &out[(size_t)node * OUTF];
#pragma unroll
        for (int j4 = 0; j4 < OUTF; j4 += 4) {
            float4 v;
            v.x = acc[j4 + 0]; v.y = acc[j4 + 1]; v.z = acc[j4 + 2]; v.w = acc[j4 + 3];
            if (do_relu) {
                v.x = fmaxf(v.x, 0.f); v.y = fmaxf(v.y, 0.f);
                v.z = fmaxf(v.z, 0.f); v.w = fmaxf(v.w, 0.f);
            }
            *(float4*)&o[j4] = v;
        }
    }
}

extern "C" void kernel_launch(void* const* d_in, const int* in_sizes, int n_in,
                              void* d_out, int out_size, void* d_ws, size_t ws_size,
                              hipStream_t stream) {
    const float* feat = (const float*)d_in[0];
    const int*   src  = (const int*)d_in[1];
    const int*   dst  = (const int*)d_in[2];
    const float* W1   = (const float*)d_in[3];
    const float* b1   = (const float*)d_in[4];
    const float* W2   = (const float*)d_in[5];
    const float* b2   = (const float*)d_in[6];
    float* out = (float*)d_out;

    const int N = in_sizes[0] / NF;   // 100000
    const int E = in_sizes[1];        // 1600000
    const int NFtot = N * NF;

    float* ws   = (float*)d_ws;
    float* dinv = ws;                                   // N
    float* agg  = ws + ((N + 255) / 256) * 256;         // N*64 (also holds X2)
    float* X1   = agg + (size_t)NFtot;                  // N*64
    float* H    = X1 + (size_t)NFtot;                   // N*64

    const int TB = 256;
    dim3 blk(TB);
    dim3 gE((E + TB - 1) / TB);
    dim3 gN((N + TB - 1) / TB);
    dim3 gNF((NFtot + TB - 1) / TB);
    dim3 gScat(((size_t)E * 64 + TB - 1) / TB);
    dim3 gGemm((N + 255) / 256);

    // degree -> d^{-1/2}
    hipMemsetAsync(dinv, 0, (size_t)N * sizeof(float), stream);
    deg_kernel<<<gE, blk, 0, stream>>>(dst, dinv, E);
    dinv_kernel<<<gN, blk, 0, stream>>>(dinv, N);

    // ---- layer 1 ----
    hipMemsetAsync(agg, 0, (size_t)NFtot * sizeof(float), stream);
    scatter_kernel<<<gScat, blk, 0, stream>>>(feat, src, dst, dinv, agg, E);
    x1_kernel<<<gNF, blk, 0, stream>>>(agg, dinv, X1, NFtot);

    hipMemsetAsync(agg, 0, (size_t)NFtot * sizeof(float), stream);
    scatter_kernel<<<gScat, blk, 0, stream>>>(X1, src, dst, dinv, agg, E);
    x2_kernel<<<gNF, blk, 0, stream>>>(agg, dinv, feat, NFtot);

    gemm_cheb<64><<<gGemm, blk, 0, stream>>>(feat, X1, agg, W1, b1, H, N, 1);

    // ---- layer 2 ----
    hipMemsetAsync(agg, 0, (size_t)NFtot * sizeof(float), stream);
    scatter_kernel<<<gScat, blk, 0, stream>>>(H, src, dst, dinv, agg, E);
    x1_kernel<<<gNF, blk, 0, stream>>>(agg, dinv, X1, NFtot);

    hipMemsetAsync(agg, 0, (size_t)NFtot * sizeof(float), stream);
    scatter_kernel<<<gScat, blk, 0, stream>>>(X1, src, dst, dinv, agg, E);
    x2_kernel<<<gNF, blk, 0, stream>>>(agg, dinv, H, NFtot);

    gemm_cheb<32><<<gGemm, blk, 0, stream>>>(H, X1, agg, W2, b2, out, N, 0);
}

// Round 2
// 665.775 us; speedup vs baseline: 2.6693x; 2.6693x over previous
//
#include <hip/hip_runtime.h>

#define NF 64   // IN_F == HID_F == 64

// ============ CSR build (counting sort by dst), rebuilt every call ============

__global__ void count_kernel(const int* __restrict__ dst, int* __restrict__ cnt, int E) {
    int e = blockIdx.x * blockDim.x + threadIdx.x;
    if (e < E) atomicAdd(&cnt[dst[e]], 1);
}

// per-block (1024 elems) sums
__global__ void block_sums(const int* __restrict__ cnt, int* __restrict__ blocksum, int n) {
    int tid = threadIdx.x;
    int base_i = blockIdx.x * 1024 + tid * 4;
    int t = 0;
#pragma unroll
    for (int j = 0; j < 4; ++j) t += (base_i + j < n) ? cnt[base_i + j] : 0;
    __shared__ int s[256];
    s[tid] = t; __syncthreads();
    for (int off = 128; off > 0; off >>= 1) {
        if (tid < off) s[tid] += s[tid + off];
        __syncthreads();
    }
    if (tid == 0) blocksum[blockIdx.x] = s[0];
}

// single block: exclusive scan of <=256 block sums; writes rowptr[n]=total
__global__ void scan_blocksums(int* __restrict__ blocksum, int* __restrict__ rowptr,
                               int nb, int n) {
    int tid = threadIdx.x;
    int v = (tid < nb) ? blocksum[tid] : 0;
    __shared__ int s[256];
    s[tid] = v; __syncthreads();
    for (int off = 1; off < 256; off <<= 1) {
        int t = (tid >= off) ? s[tid - off] : 0;
        __syncthreads();
        s[tid] += t;
        __syncthreads();
    }
    if (tid < nb) blocksum[tid] = s[tid] - v;   // exclusive
    if (tid == 255) rowptr[n] = s[255];         // total == E
}

// per-element exclusive scan -> rowptr; also dinv = rsqrt(max(deg,1)); cnt reset to 0
__global__ void scan_finalize(int* __restrict__ cnt, const int* __restrict__ blocksum,
                              int* __restrict__ rowptr, float* __restrict__ dinv, int n) {
    int tid = threadIdx.x;
    int base_i = blockIdx.x * 1024 + tid * 4;
    int v[4]; int tsum = 0;
#pragma unroll
    for (int j = 0; j < 4; ++j) { v[j] = (base_i + j < n) ? cnt[base_i + j] : 0; tsum += v[j]; }
    __shared__ int s[256];
    s[tid] = tsum; __syncthreads();
    for (int off = 1; off < 256; off <<= 1) {
        int t = (tid >= off) ? s[tid - off] : 0;
        __syncthreads();
        s[tid] += t;
        __syncthreads();
    }
    int base = blocksum[blockIdx.x] + (s[tid] - tsum);
#pragma unroll
    for (int j = 0; j < 4; ++j) {
        int i = base_i + j;
        if (i < n) {
            rowptr[i] = base;
            dinv[i] = rsqrtf(fmaxf((float)v[j], 1.0f));
            cnt[i] = 0;       // reused as cursor by fill_kernel
            base += v[j];
        }
    }
}

__global__ void fill_kernel(const int* __restrict__ src, const int* __restrict__ dst,
                            const int* __restrict__ rowptr, int* __restrict__ cursor,
                            int* __restrict__ csr_src, int E) {
    int e = blockIdx.x * blockDim.x + threadIdx.x;
    if (e < E) {
        int d = dst[e];
        int pos = rowptr[d] + atomicAdd(&cursor[d], 1);
        csr_src[pos] = src[e];
    }
}

// ============ SpMM as gather: one wave per dst node, lane = feature ============
// mode 1: out = -spmm(X)            (X1 recurrence, RE_NORM==1)
// mode 2: out = -2*spmm(X) - Xprev  (X2 recurrence)
__launch_bounds__(256)
__global__ void spmm_gather(const float* __restrict__ X, const int* __restrict__ rowptr,
                            const int* __restrict__ csr_src, const float* __restrict__ dinv,
                            const float* __restrict__ Xprev, float* __restrict__ out,
                            int n, int mode) {
    int node = (blockIdx.x * blockDim.x + threadIdx.x) >> 6;
    int f = threadIdx.x & 63;
    if (node >= n) return;
    int beg = rowptr[node];
    int end = rowptr[node + 1];
    float acc = 0.0f;
    int e = beg;
    for (; e + 4 <= end; e += 4) {
        int s0 = csr_src[e + 0];
        int s1 = csr_src[e + 1];
        int s2 = csr_src[e + 2];
        int s3 = csr_src[e + 3];
        float v0 = X[(size_t)s0 * NF + f] * dinv[s0];
        float v1 = X[(size_t)s1 * NF + f] * dinv[s1];
        float v2 = X[(size_t)s2 * NF + f] * dinv[s2];
        float v3 = X[(size_t)s3 * NF + f] * dinv[s3];
        acc += v0 + v1 + v2 + v3;
    }
    for (; e < end; ++e) {
        int s = csr_src[e];
        acc += X[(size_t)s * NF + f] * dinv[s];
    }
    float r;
    if (mode == 1) r = -acc * dinv[node];
    else           r = -2.0f * acc * dinv[node] - Xprev[(size_t)node * NF + f];
    out[(size_t)node * NF + f] = r;
}

// ============ GEMM: out[n, OUTF] = relu?([X0|X1|X2] @ W + b) ============
template <int OUTF>
__launch_bounds__(256)
__global__ void gemm_cheb(const float* __restrict__ X0, const float* __restrict__ X1,
                          const float* __restrict__ X2, const float* __restrict__ W,
                          const float* __restrict__ bias, float* __restrict__ out,
                          int n, int do_relu) {
    __shared__ float xs[256 * 65];
    const int tid = threadIdx.x;
    const int node0 = blockIdx.x * 256;
    const int node = node0 + tid;

    float acc[OUTF];
#pragma unroll
    for (int j = 0; j < OUTF; ++j) acc[j] = bias[j];

    const float* Xp[3] = {X0, X1, X2};
#pragma unroll 1
    for (int p = 0; p < 3; ++p) {
        const float* __restrict__ Xc = Xp[p];
#pragma unroll
        for (int j = 0; j < 16; ++j) {
            int idx4 = j * 256 + tid;
            int ln = idx4 >> 4;
            int k4 = (idx4 & 15) * 4;
            float4 v = make_float4(0.f, 0.f, 0.f, 0.f);
            int gnode = node0 + ln;
            if (gnode < n) v = *(const float4*)&Xc[(size_t)gnode * 64 + k4];
            float* s = &xs[ln * 65 + k4];
            s[0] = v.x; s[1] = v.y; s[2] = v.z; s[3] = v.w;
        }
        __syncthreads();

        const float* __restrict__ Wp = W + (size_t)p * 64 * OUTF;
        for (int k = 0; k < 64; ++k) {
            float x = xs[tid * 65 + k];
#pragma unroll
            for (int j = 0; j < OUTF; ++j)
                acc[j] += x * Wp[k * OUTF + j];
        }
        __syncthreads();
    }

    if (node < n) {
        float* o = &out[(size_t)node * OUTF];
#pragma unroll
        for (int j4 = 0; j4 < OUTF; j4 += 4) {
            float4 v;
            v.x = acc[j4 + 0]; v.y = acc[j4 + 1]; v.z = acc[j4 + 2]; v.w = acc[j4 + 3];
            if (do_relu) {
                v.x = fmaxf(v.x, 0.f); v.y = fmaxf(v.y, 0.f);
                v.z = fmaxf(v.z, 0.f); v.w = fmaxf(v.w, 0.f);
            }
            *(float4*)&o[j4] = v;
        }
    }
}

extern "C" void kernel_launch(void* const* d_in, const int* in_sizes, int n_in,
                              void* d_out, int out_size, void* d_ws, size_t ws_size,
                              hipStream_t stream) {
    const float* feat = (const float*)d_in[0];
    const int*   src  = (const int*)d_in[1];
    const int*   dst  = (const int*)d_in[2];
    const float* W1   = (const float*)d_in[3];
    const float* b1   = (const float*)d_in[4];
    const float* W2   = (const float*)d_in[5];
    const float* b2   = (const float*)d_in[6];
    float* out = (float*)d_out;

    const int N = in_sizes[0] / NF;   // 100000
    const int E = in_sizes[1];        // 1600000
    const size_t NFtot = (size_t)N * NF;

    // workspace layout
    char* p = (char*)d_ws;
    int* cnt      = (int*)p;        p += ((size_t)N + 256) * 4;
    int* rowptr   = (int*)p;        p += ((size_t)N + 256) * 4;
    int* csr_src  = (int*)p;        p += (size_t)E * 4;
    int* blocksum = (int*)p;        p += 256 * 4;
    float* dinv   = (float*)p;      p += ((size_t)N + 256) * 4;
    float* X1     = (float*)p;      p += NFtot * 4;
    float* X2     = (float*)p;      p += NFtot * 4;
    float* H      = (float*)p;      p += NFtot * 4;

    const int TB = 256;
    dim3 blk(TB);
    dim3 gE((E + TB - 1) / TB);
    const int nb = (N + 1023) / 1024;   // 98 for N=100k (must be <=256)
    dim3 gScan(nb);
    dim3 gWave(((size_t)N * 64 + TB - 1) / TB);
    dim3 gGemm((N + 255) / 256);

    // ---- CSR build ----
    hipMemsetAsync(cnt, 0, (size_t)N * sizeof(int), stream);
    count_kernel<<<gE, blk, 0, stream>>>(dst, cnt, E);
    block_sums<<<gScan, blk, 0, stream>>>(cnt, blocksum, N);
    scan_blocksums<<<1, blk, 0, stream>>>(blocksum, rowptr, nb, N);
    scan_finalize<<<gScan, blk, 0, stream>>>(cnt, blocksum, rowptr, dinv, N);
    fill_kernel<<<gE, blk, 0, stream>>>(src, dst, rowptr, cnt, csr_src, E);

    // ---- layer 1 ----
    spmm_gather<<<gWave, blk, 0, stream>>>(feat, rowptr, csr_src, dinv, nullptr, X1, N, 1);
    spmm_gather<<<gWave, blk, 0, stream>>>(X1, rowptr, csr_src, dinv, feat, X2, N, 2);
    gemm_cheb<64><<<gGemm, blk, 0, stream>>>(feat, X1, X2, W1, b1, H, N, 1);

    // ---- layer 2 ----
    spmm_gather<<<gWave, blk, 0, stream>>>(H, rowptr, csr_src, dinv, nullptr, X1, N, 1);
    spmm_gather<<<gWave, blk, 0, stream>>>(X1, rowptr, csr_src, dinv, H, X2, N, 2);
    gemm_cheb<32><<<gGemm, blk, 0, stream>>>(H, X1, X2, W2, b2, out, N, 0);
}